// Round 1
// baseline (1784.971 us; speedup 1.0000x reference)
//
#include <hip/hip_runtime.h>
#include <stdint.h>

#define S_LEN 2048
#define D_HEAD 64
#define N_B 2
#define N_H 16

typedef __attribute__((ext_vector_type(8))) short bf16x8;
typedef __attribute__((ext_vector_type(4))) float f32x4;

__device__ __forceinline__ short f2bf(float f) {
    union { float f; uint32_t u; } x; x.f = f;
    uint32_t u = x.u;
    u += 0x7FFFu + ((u >> 16) & 1u);   // RNE to bf16
    return (short)(u >> 16);
}

// Pack int32 mask -> 1 bit per element. One thread per element, ballot per wave.
__global__ void maskbits_kernel(const int* __restrict__ mask,
                                unsigned long long* __restrict__ bits) {
    int tid = blockIdx.x * 256 + threadIdx.x;
    unsigned long long b = __ballot(mask[tid] != 0);
    if ((threadIdx.x & 63) == 0) bits[tid >> 6] = b;
}

// Fused attention: per workgroup = one (b,h) x 64 q-rows; 4 waves x 16 rows.
// Pass 1: scores -> write attn, online max/sumexp. Pass 2: recompute scores,
// write attn_prob, accumulate O = P*V via LDS transpose of P.
template <int USE_BITS>
__global__ __launch_bounds__(256) void attn_fused(
    const float* __restrict__ qg, const float* __restrict__ kg,
    const float* __restrict__ vg, const int* __restrict__ mask32,
    const uint32_t* __restrict__ mbits,
    float* __restrict__ out_o, float* __restrict__ out_p,
    float* __restrict__ out_s)
{
    __shared__ short pbuf[4][16][72];   // per-wave P tile, stride 72 (=144B, 16B-aligned, conflict-free-ish)

    const int tile = blockIdx.x;        // 0..1023
    const int bh   = tile >> 5;         // 0..31
    const int qt   = tile & 31;
    const int b    = bh >> 4;

    const float* qp = qg + (size_t)bh * S_LEN * D_HEAD;
    const float* kp = kg + (size_t)bh * S_LEN * D_HEAD;
    const float* vp = vg + (size_t)bh * S_LEN * D_HEAD;
    const int*      mrow = mask32 + (size_t)b * S_LEN * S_LEN;
    const uint32_t* brow = mbits  + (size_t)b * (S_LEN * (S_LEN / 32));

    const int wave = threadIdx.x >> 6;
    const int lane = threadIdx.x & 63;
    const int col  = lane & 15;
    const int quad = lane >> 4;
    const int q0   = qt * 64 + wave * 16;   // this wave's first q row (absolute in S)

    // --- persistent Q fragments (A operand), scaled by 1/TEMPERATURE ---
    bf16x8 aq[2];
    {
        const float* qr = qp + (size_t)(q0 + col) * D_HEAD + quad * 8;
        #pragma unroll
        for (int h = 0; h < 2; ++h) {
            const f32x4* p4 = (const f32x4*)(qr + h * 32);
            f32x4 x0 = p4[0], x1 = p4[1];
            #pragma unroll
            for (int j = 0; j < 4; ++j) {
                aq[h][j]     = f2bf(x0[j] * 0.125f);
                aq[h][4 + j] = f2bf(x1[j] * 0.125f);
            }
        }
    }

    float m_run[4], l_run[4];
    #pragma unroll
    for (int r = 0; r < 4; ++r) { m_run[r] = -__builtin_inff(); l_run[r] = 0.f; }

    float* srow = out_s + ((size_t)bh * S_LEN + q0) * S_LEN;
    float* prow = out_p + ((size_t)bh * S_LEN + q0) * S_LEN;

    // ================= pass 1 =================
    for (int kt = 0; kt < 32; ++kt) {
        const int kbase = kt * 64;
        float sc[4][4];   // [ktile16][reg/row]
        #pragma unroll
        for (int t = 0; t < 4; ++t) {
            f32x4 c = {0.f, 0.f, 0.f, 0.f};
            const float* kr = kp + (size_t)(kbase + t * 16 + col) * D_HEAD + quad * 8;
            #pragma unroll
            for (int h = 0; h < 2; ++h) {
                const f32x4* p4 = (const f32x4*)(kr + h * 32);
                f32x4 x0 = p4[0], x1 = p4[1];
                bf16x8 bk;
                #pragma unroll
                for (int j = 0; j < 4; ++j) { bk[j] = f2bf(x0[j]); bk[4 + j] = f2bf(x1[j]); }
                c = __builtin_amdgcn_mfma_f32_16x16x32_bf16(aq[h], bk, c, 0, 0, 0);
            }
            #pragma unroll
            for (int r = 0; r < 4; ++r) sc[t][r] = c[r];
        }
        // mask add + store attn
        #pragma unroll
        for (int r = 0; r < 4; ++r) {
            const int qr = q0 + quad * 4 + r;
            uint32_t w0 = 0, w1 = 0;
            if (USE_BITS) {
                const uint32_t* wp = brow + (size_t)qr * (S_LEN / 32) + (kbase >> 5);
                w0 = wp[0]; w1 = wp[1];
            }
            #pragma unroll
            for (int t = 0; t < 4; ++t) {
                int on;
                if (USE_BITS) {
                    uint32_t w = (t < 2) ? w0 : w1;
                    on = (w >> (((t & 1) << 4) + col)) & 1u;
                } else {
                    on = mrow[(size_t)qr * S_LEN + kbase + t * 16 + col] != 0;
                }
                float val = sc[t][r] + (on ? 0.f : -1e9f);
                sc[t][r] = val;
                srow[(size_t)(quad * 4 + r) * S_LEN + kbase + t * 16 + col] = val;
            }
        }
        // online softmax stats (row values live in this quad's 16 lanes)
        #pragma unroll
        for (int r = 0; r < 4; ++r) {
            float x = fmaxf(fmaxf(sc[0][r], sc[1][r]), fmaxf(sc[2][r], sc[3][r]));
            x = fmaxf(x, __shfl_xor(x, 1));
            x = fmaxf(x, __shfl_xor(x, 2));
            x = fmaxf(x, __shfl_xor(x, 4));
            x = fmaxf(x, __shfl_xor(x, 8));
            float mnew  = fmaxf(m_run[r], x);
            float alpha = __expf(m_run[r] - mnew);   // -inf -> 0 on first tile
            float ss = __expf(sc[0][r] - mnew) + __expf(sc[1][r] - mnew)
                     + __expf(sc[2][r] - mnew) + __expf(sc[3][r] - mnew);
            ss += __shfl_xor(ss, 1);
            ss += __shfl_xor(ss, 2);
            ss += __shfl_xor(ss, 4);
            ss += __shfl_xor(ss, 8);
            l_run[r] = l_run[r] * alpha + ss;
            m_run[r] = mnew;
        }
    }

    float inv_l[4];
    #pragma unroll
    for (int r = 0; r < 4; ++r) inv_l[r] = 1.f / l_run[r];

    f32x4 acc[4];
    #pragma unroll
    for (int n = 0; n < 4; ++n) acc[n] = (f32x4){0.f, 0.f, 0.f, 0.f};

    // ================= pass 2 =================
    for (int kt = 0; kt < 32; ++kt) {
        const int kbase = kt * 64;
        float pv[4][4];
        #pragma unroll
        for (int t = 0; t < 4; ++t) {
            f32x4 c = {0.f, 0.f, 0.f, 0.f};
            const float* kr = kp + (size_t)(kbase + t * 16 + col) * D_HEAD + quad * 8;
            #pragma unroll
            for (int h = 0; h < 2; ++h) {
                const f32x4* p4 = (const f32x4*)(kr + h * 32);
                f32x4 x0 = p4[0], x1 = p4[1];
                bf16x8 bk;
                #pragma unroll
                for (int j = 0; j < 4; ++j) { bk[j] = f2bf(x0[j]); bk[4 + j] = f2bf(x1[j]); }
                c = __builtin_amdgcn_mfma_f32_16x16x32_bf16(aq[h], bk, c, 0, 0, 0);
            }
            #pragma unroll
            for (int r = 0; r < 4; ++r) pv[t][r] = c[r];
        }
        #pragma unroll
        for (int r = 0; r < 4; ++r) {
            const int qr = q0 + quad * 4 + r;
            uint32_t w0 = 0, w1 = 0;
            if (USE_BITS) {
                const uint32_t* wp = brow + (size_t)qr * (S_LEN / 32) + (kbase >> 5);
                w0 = wp[0]; w1 = wp[1];
            }
            #pragma unroll
            for (int t = 0; t < 4; ++t) {
                int on;
                if (USE_BITS) {
                    uint32_t w = (t < 2) ? w0 : w1;
                    on = (w >> (((t & 1) << 4) + col)) & 1u;
                } else {
                    on = mrow[(size_t)qr * S_LEN + kbase + t * 16 + col] != 0;
                }
                float s = pv[t][r] + (on ? 0.f : -1e9f);
                float p = __expf(s - m_run[r]) * inv_l[r];
                prow[(size_t)(quad * 4 + r) * S_LEN + kbase + t * 16 + col] = p;
                pv[t][r] = p;
            }
        }
        __syncthreads();
        // P (C layout: lane=col over k, rows in regs) -> LDS [q][k]
        #pragma unroll
        for (int t = 0; t < 4; ++t)
            #pragma unroll
            for (int r = 0; r < 4; ++r)
                pbuf[wave][quad * 4 + r][t * 16 + col] = f2bf(pv[t][r]);
        __syncthreads();
        // O += P * V
        #pragma unroll
        for (int c2 = 0; c2 < 2; ++c2) {
            bf16x8 ap = *(const bf16x8*)&pbuf[wave][col][c2 * 32 + quad * 8];
            #pragma unroll
            for (int n = 0; n < 4; ++n) {
                bf16x8 bv;
                const float* vcol = vp + (size_t)(kbase + c2 * 32 + quad * 8) * D_HEAD + n * 16 + col;
                #pragma unroll
                for (int j = 0; j < 8; ++j) bv[j] = f2bf(vcol[(size_t)j * D_HEAD]);
                acc[n] = __builtin_amdgcn_mfma_f32_16x16x32_bf16(ap, bv, acc[n], 0, 0, 0);
            }
        }
    }

    // epilogue: store O
    float* orow = out_o + ((size_t)bh * S_LEN + q0) * D_HEAD;
    #pragma unroll
    for (int n = 0; n < 4; ++n)
        #pragma unroll
        for (int r = 0; r < 4; ++r)
            orow[(size_t)(quad * 4 + r) * D_HEAD + n * 16 + col] = acc[n][r];
}

extern "C" void kernel_launch(void* const* d_in, const int* in_sizes, int n_in,
                              void* d_out, int out_size, void* d_ws, size_t ws_size,
                              hipStream_t stream) {
    const float* q    = (const float*)d_in[0];
    const float* k    = (const float*)d_in[1];
    const float* v    = (const float*)d_in[2];
    const int*   mask = (const int*)d_in[3];

    float* out_o = (float*)d_out;                                   // [B,H,S,D]
    float* out_p = out_o + (size_t)N_B * N_H * S_LEN * D_HEAD;      // [B,H,S,S]
    float* out_s = out_p + (size_t)N_B * N_H * (size_t)S_LEN * S_LEN;

    const size_t bits_bytes = (size_t)N_B * S_LEN * (S_LEN / 8);    // 1 MiB
    const int nblocks = N_B * N_H * (S_LEN / 64);                   // 1024

    if (ws_size >= bits_bytes) {
        maskbits_kernel<<<(N_B * S_LEN * S_LEN) / 256, 256, 0, stream>>>(
            mask, (unsigned long long*)d_ws);
        attn_fused<1><<<nblocks, 256, 0, stream>>>(
            q, k, v, mask, (const uint32_t*)d_ws, out_o, out_p, out_s);
    } else {
        attn_fused<0><<<nblocks, 256, 0, stream>>>(
            q, k, v, mask, (const uint32_t*)nullptr, out_o, out_p, out_s);
    }
}